// Round 2
// baseline (1146.763 us; speedup 1.0000x reference)
//
#include <hip/hip_runtime.h>
#include <hip/hip_bf16.h>
#include <stdint.h>

typedef __attribute__((ext_vector_type(8))) short short8;
typedef __attribute__((ext_vector_type(4))) float floatx4;

// Q pre-scale: 0.125 (the 1/sqrt(K)) * log2(e), so exp(s/8) == exp2(q'.k)
#define QSCALE 0.18033688f

__device__ __forceinline__ unsigned short f2bf(float f) {
    unsigned int u = __float_as_uint(f);
    u += 0x7fffu + ((u >> 16) & 1u);
    return (unsigned short)(u >> 16);
}

__device__ __forceinline__ unsigned int pack2bf(float a, float b) {
    __hip_bfloat162 h = __float22bfloat162_rn(make_float2(a, b));
    return *reinterpret_cast<unsigned int*>(&h);
}

// drp tile base: C-layout 16x16 tiles, element (row=quad*4+r,col=lr) at lane*4+r
__device__ __forceinline__ size_t drp_base(int b, int lt, int mt) {
    return ((((size_t)b * 128 + lt) * 128 + mt) << 8);
}

// ---------------------------------------------------------------------------
// Kernel 1: QKV GEMM  C[8192,3072] = x[8192,1024] @ wqkv[1024,3072]
// Epilogue scatters into qb (scaled by QSCALE) / kb [b,h,2048,64] and
// vbt [b,h,64,2048] (V pre-transposed for PV B-fragments).
// ---------------------------------------------------------------------------
__global__ __launch_bounds__(256) void qkv_gemm(
    const float* __restrict__ A, const float* __restrict__ B,
    unsigned short* __restrict__ qb, unsigned short* __restrict__ kb,
    unsigned short* __restrict__ vbt)
{
    __shared__ __align__(16) unsigned short As[128 * 40];
    __shared__ __align__(16) unsigned short Bs[128 * 40]; // transposed [n][k]
    const int tid = threadIdx.x;
    const int wave = tid >> 6, lane = tid & 63;
    const int quad = lane >> 4, lr = lane & 15;
    const int wr = wave >> 1, wc = wave & 1;
    const int bm = blockIdx.y * 128, bn = blockIdx.x * 128;

    floatx4 acc[4][4];
    #pragma unroll
    for (int i = 0; i < 4; i++)
        #pragma unroll
        for (int j = 0; j < 4; j++) acc[i][j] = (floatx4)0.0f;

    for (int k0 = 0; k0 < 1024; k0 += 32) {
        #pragma unroll
        for (int i = 0; i < 4; i++) {            // stage A: 128x32 fp32->bf16
            int idx = tid + 256 * i;
            int row = idx >> 3, c4 = (idx & 7) * 4;
            const float4 v = *(const float4*)(A + (size_t)(bm + row) * 1024 + k0 + c4);
            ushort4 o; o.x = f2bf(v.x); o.y = f2bf(v.y); o.z = f2bf(v.z); o.w = f2bf(v.w);
            *(ushort4*)&As[row * 40 + c4] = o;
        }
        #pragma unroll
        for (int i = 0; i < 4; i++) {            // stage B: 32x128 -> [n][k]
            int idx = tid + 256 * i;
            int kr = idx >> 5, c4 = (idx & 31) * 4;
            const float4 v = *(const float4*)(B + (size_t)(k0 + kr) * 3072 + bn + c4);
            Bs[(c4 + 0) * 40 + kr] = f2bf(v.x);
            Bs[(c4 + 1) * 40 + kr] = f2bf(v.y);
            Bs[(c4 + 2) * 40 + kr] = f2bf(v.z);
            Bs[(c4 + 3) * 40 + kr] = f2bf(v.w);
        }
        __syncthreads();
        short8 af[4], bfr[4];
        #pragma unroll
        for (int i = 0; i < 4; i++)
            af[i] = *(const short8*)&As[(wr * 64 + i * 16 + lr) * 40 + quad * 8];
        #pragma unroll
        for (int j = 0; j < 4; j++)
            bfr[j] = *(const short8*)&Bs[(wc * 64 + j * 16 + lr) * 40 + quad * 8];
        #pragma unroll
        for (int i = 0; i < 4; i++)
            #pragma unroll
            for (int j = 0; j < 4; j++)
                acc[i][j] = __builtin_amdgcn_mfma_f32_16x16x32_bf16(af[i], bfr[j], acc[i][j], 0, 0, 0);
        __syncthreads();
    }
    #pragma unroll
    for (int i = 0; i < 4; i++)
        #pragma unroll
        for (int j = 0; j < 4; j++)
            #pragma unroll
            for (int r = 0; r < 4; r++) {
                int row = bm + wr * 64 + i * 16 + quad * 4 + r;
                int col = bn + wc * 64 + j * 16 + lr;
                int b = row >> 11, l = row & 2047;
                int part = col >> 10, d = col & 1023;
                int flat = (l << 10) | d;
                int h = flat >> 17;
                int rem = flat & 131071;
                int l2 = rem >> 6, kk = rem & 63;
                float av = acc[i][j][r];
                if (part == 0) {
                    size_t dst = ((size_t)((b * 16 + h) * 2048 + l2) << 6) + kk;
                    qb[dst] = f2bf(av * QSCALE);
                } else if (part == 1) {
                    size_t dst = ((size_t)((b * 16 + h) * 2048 + l2) << 6) + kk;
                    kb[dst] = f2bf(av);
                } else {
                    size_t dst = (((size_t)(b * 16 + h) * 64 + kk) << 11) + l2;
                    vbt[dst] = f2bf(av);
                }
            }
}

// ---------------------------------------------------------------------------
// Kernel 2: denominator  drp = bf16(1/sum_h exp2(q'.k)) in C-layout tile order
// Block = (b, 32x32 (l,m) tile); wave w owns heads 4w..4w+3; LDS reduce;
// each wave stores one 16x16 output tile with a single coalesced ushort4/lane.
// ---------------------------------------------------------------------------
__global__ __launch_bounds__(256) void attn_denom(
    const unsigned short* __restrict__ qb, const unsigned short* __restrict__ kb,
    unsigned short* __restrict__ drp)
{
    __shared__ float Ered[4][32][33];
    const int tid = threadIdx.x;
    const int wave = tid >> 6, lane = tid & 63, quad = lane >> 4, lr = lane & 15;
    const int m0 = blockIdx.x * 32, l0 = blockIdx.y * 32, b = blockIdx.z;

    floatx4 e[2][2];
    #pragma unroll
    for (int i = 0; i < 2; i++)
        #pragma unroll
        for (int j = 0; j < 2; j++) e[i][j] = (floatx4)0.0f;

    for (int hh = 0; hh < 4; hh++) {
        const int h = wave * 4 + hh;
        const unsigned short* qbase = qb + ((size_t)(b * 16 + h) * 2048) * 64;
        const unsigned short* kbase = kb + ((size_t)(b * 16 + h) * 2048) * 64;
        short8 qf[2][2], kf[2][2];
        #pragma unroll
        for (int it = 0; it < 2; it++)
            #pragma unroll
            for (int f = 0; f < 2; f++)
                qf[it][f] = *(const short8*)(qbase + (size_t)(l0 + it * 16 + lr) * 64 + f * 32 + quad * 8);
        #pragma unroll
        for (int jt = 0; jt < 2; jt++)
            #pragma unroll
            for (int f = 0; f < 2; f++)
                kf[jt][f] = *(const short8*)(kbase + (size_t)(m0 + jt * 16 + lr) * 64 + f * 32 + quad * 8);
        #pragma unroll
        for (int it = 0; it < 2; it++)
            #pragma unroll
            for (int jt = 0; jt < 2; jt++) {
                floatx4 s = (floatx4)0.0f;
                s = __builtin_amdgcn_mfma_f32_16x16x32_bf16(qf[it][0], kf[jt][0], s, 0, 0, 0);
                s = __builtin_amdgcn_mfma_f32_16x16x32_bf16(qf[it][1], kf[jt][1], s, 0, 0, 0);
                #pragma unroll
                for (int r = 0; r < 4; r++)
                    e[it][jt][r] += __builtin_amdgcn_exp2f(s[r]);
            }
    }
    #pragma unroll
    for (int it = 0; it < 2; it++)
        #pragma unroll
        for (int jt = 0; jt < 2; jt++)
            #pragma unroll
            for (int r = 0; r < 4; r++)
                Ered[wave][it * 16 + quad * 4 + r][jt * 16 + lr] = e[it][jt][r];
    __syncthreads();
    // wave w -> output sub-tile (it = w>>1, jt = w&1); coalesced C-layout store
    {
        const int it = wave >> 1, jt = wave & 1;
        float rc[4];
        #pragma unroll
        for (int r = 0; r < 4; r++) {
            int ll = it * 16 + quad * 4 + r, mm = jt * 16 + lr;
            float sum = Ered[0][ll][mm] + Ered[1][ll][mm] + Ered[2][ll][mm] + Ered[3][ll][mm];
            rc[r] = __builtin_amdgcn_rcpf(sum);
        }
        uint2 o;
        o.x = pack2bf(rc[0], rc[1]);
        o.y = pack2bf(rc[2], rc[3]);
        size_t base = drp_base(b, (l0 >> 4) + it, (m0 >> 4) + jt);
        *(uint2*)(drp + base + (size_t)lane * 4) = o;
    }
}

// ---------------------------------------------------------------------------
// Kernel 3: P@V per (b,h,64-l tile). Zero barriers in the m-loop:
//  - K fragments + pre-transposed V^T fragments straight from global
//  - drp read as one coalesced uint2 per lane per 16-m tile
//  - per-wave-private LDS round-trip for P (C-layout -> A-layout)
// Writes concat layout cb[b*2048+l, h*64+k] bf16.
// ---------------------------------------------------------------------------
__global__ __launch_bounds__(256) void attn_pv(
    const unsigned short* __restrict__ qb, const unsigned short* __restrict__ kb,
    const unsigned short* __restrict__ vbt, const unsigned short* __restrict__ drp,
    unsigned short* __restrict__ cb)
{
    __shared__ __align__(16) unsigned short Pl[4][16 * 72];   // per-wave [l][m64+pad]
    const int tid = threadIdx.x;
    const int wave = tid >> 6, lane = tid & 63, quad = lane >> 4, lr = lane & 15;
    const int l0 = blockIdx.x * 64, h = blockIdx.y, b = blockIdx.z;
    const size_t head = (size_t)(b * 16 + h);
    const unsigned short* qbase = qb + head * 2048 * 64;
    const unsigned short* kbase = kb + head * 2048 * 64;
    const unsigned short* vtb  = vbt + (head << 17);          // [64][2048]
    const int lw = l0 + wave * 16;
    const int lt = lw >> 4;
    unsigned short* pl = &Pl[wave][0];

    const short8 qf0 = *(const short8*)(qbase + (size_t)(lw + lr) * 64 + quad * 8);
    const short8 qf1 = *(const short8*)(qbase + (size_t)(lw + lr) * 64 + 32 + quad * 8);
    floatx4 acc[4];
    #pragma unroll
    for (int n = 0; n < 4; n++) acc[n] = (floatx4)0.0f;

    for (int m0 = 0; m0 < 2048; m0 += 64) {
        // coalesced reciprocal-denominator tiles (prefetch all 4)
        uint2 du[4];
        #pragma unroll
        for (int jt = 0; jt < 4; jt++)
            du[jt] = *(const uint2*)(drp + drp_base(b, lt, (m0 >> 4) + jt) + (size_t)lane * 4);

        #pragma unroll
        for (int jt = 0; jt < 4; jt++) {
            const short8 kf0 = *(const short8*)(kbase + (size_t)(m0 + jt * 16 + lr) * 64 + quad * 8);
            const short8 kf1 = *(const short8*)(kbase + (size_t)(m0 + jt * 16 + lr) * 64 + 32 + quad * 8);
            floatx4 s = (floatx4)0.0f;
            s = __builtin_amdgcn_mfma_f32_16x16x32_bf16(qf0, kf0, s, 0, 0, 0);
            s = __builtin_amdgcn_mfma_f32_16x16x32_bf16(qf1, kf1, s, 0, 0, 0);
            // reciprocals: bf16 pairs -> fp32 by shift/mask
            float r0 = __uint_as_float(du[jt].x << 16);
            float r1 = __uint_as_float(du[jt].x & 0xffff0000u);
            float r2 = __uint_as_float(du[jt].y << 16);
            float r3 = __uint_as_float(du[jt].y & 0xffff0000u);
            float p0 = __builtin_amdgcn_exp2f(s[0]) * r0;
            float p1 = __builtin_amdgcn_exp2f(s[1]) * r1;
            float p2 = __builtin_amdgcn_exp2f(s[2]) * r2;
            float p3 = __builtin_amdgcn_exp2f(s[3]) * r3;
            unsigned int u01 = pack2bf(p0, p1);
            unsigned int u23 = pack2bf(p2, p3);
            const int col = jt * 16 + lr;
            pl[(quad * 4 + 0) * 72 + col] = (unsigned short)u01;
            pl[(quad * 4 + 1) * 72 + col] = (unsigned short)(u01 >> 16);
            pl[(quad * 4 + 2) * 72 + col] = (unsigned short)u23;
            pl[(quad * 4 + 3) * 72 + col] = (unsigned short)(u23 >> 16);
        }
        // P in A-layout (wave-private LDS: no barrier needed)
        const short8 pa0 = *(const short8*)&pl[lr * 72 + quad * 8];
        const short8 pa1 = *(const short8*)&pl[lr * 72 + 32 + quad * 8];
        #pragma unroll
        for (int n = 0; n < 4; n++) {
            const short8 vf0 = *(const short8*)(vtb + (size_t)(n * 16 + lr) * 2048 + m0 + quad * 8);
            const short8 vf1 = *(const short8*)(vtb + (size_t)(n * 16 + lr) * 2048 + m0 + 32 + quad * 8);
            acc[n] = __builtin_amdgcn_mfma_f32_16x16x32_bf16(pa0, vf0, acc[n], 0, 0, 0);
            acc[n] = __builtin_amdgcn_mfma_f32_16x16x32_bf16(pa1, vf1, acc[n], 0, 0, 0);
        }
    }
    #pragma unroll
    for (int n = 0; n < 4; n++)
        #pragma unroll
        for (int r = 0; r < 4; r++) {
            int l = lw + quad * 4 + r;
            int col = h * 64 + n * 16 + lr;
            cb[(size_t)(b * 2048 + l) * 1024 + col] = f2bf(acc[n][r]);
        }
}

// ---------------------------------------------------------------------------
// Kernel 4: output GEMM  out[8192,1024] = concat[8192,1024] @ wo[1024,1024]
// ---------------------------------------------------------------------------
__global__ __launch_bounds__(256) void out_gemm(
    const unsigned short* __restrict__ A, const float* __restrict__ B,
    float* __restrict__ C)
{
    __shared__ __align__(16) unsigned short As[128 * 40];
    __shared__ __align__(16) unsigned short Bs[128 * 40];
    const int tid = threadIdx.x;
    const int wave = tid >> 6, lane = tid & 63, quad = lane >> 4, lr = lane & 15;
    const int wr = wave >> 1, wc = wave & 1;
    const int bm = blockIdx.y * 128, bn = blockIdx.x * 128;

    floatx4 acc[4][4];
    #pragma unroll
    for (int i = 0; i < 4; i++)
        #pragma unroll
        for (int j = 0; j < 4; j++) acc[i][j] = (floatx4)0.0f;

    for (int k0 = 0; k0 < 1024; k0 += 32) {
        #pragma unroll
        for (int i = 0; i < 2; i++) {            // stage A (bf16 already)
            int idx = tid + 256 * i;
            int row = idx >> 2, c8 = (idx & 3) * 8;
            short8 v = *(const short8*)(A + (size_t)(bm + row) * 1024 + k0 + c8);
            *(short8*)&As[row * 40 + c8] = v;
        }
        #pragma unroll
        for (int i = 0; i < 4; i++) {            // stage B fp32->bf16 [n][k]
            int idx = tid + 256 * i;
            int kr = idx >> 5, c4 = (idx & 31) * 4;
            const float4 v = *(const float4*)(B + (size_t)(k0 + kr) * 1024 + bn + c4);
            Bs[(c4 + 0) * 40 + kr] = f2bf(v.x);
            Bs[(c4 + 1) * 40 + kr] = f2bf(v.y);
            Bs[(c4 + 2) * 40 + kr] = f2bf(v.z);
            Bs[(c4 + 3) * 40 + kr] = f2bf(v.w);
        }
        __syncthreads();
        short8 af[4], bfr[4];
        #pragma unroll
        for (int i = 0; i < 4; i++)
            af[i] = *(const short8*)&As[(wr * 64 + i * 16 + lr) * 40 + quad * 8];
        #pragma unroll
        for (int j = 0; j < 4; j++)
            bfr[j] = *(const short8*)&Bs[(wc * 64 + j * 16 + lr) * 40 + quad * 8];
        #pragma unroll
        for (int i = 0; i < 4; i++)
            #pragma unroll
            for (int j = 0; j < 4; j++)
                acc[i][j] = __builtin_amdgcn_mfma_f32_16x16x32_bf16(af[i], bfr[j], acc[i][j], 0, 0, 0);
        __syncthreads();
    }
    #pragma unroll
    for (int i = 0; i < 4; i++)
        #pragma unroll
        for (int j = 0; j < 4; j++)
            #pragma unroll
            for (int r = 0; r < 4; r++) {
                int row = bm + wr * 64 + i * 16 + quad * 4 + r;
                int col = bn + wc * 64 + j * 16 + lr;
                C[(size_t)row * 1024 + col] = acc[i][j][r];
            }
}

extern "C" void kernel_launch(void* const* d_in, const int* in_sizes, int n_in,
                              void* d_out, int out_size, void* d_ws, size_t ws_size,
                              hipStream_t stream) {
    const float* x    = (const float*)d_in[0];   // [4,2048,1024]
    const float* wqkv = (const float*)d_in[1];   // [1024,3072]
    const float* wo   = (const float*)d_in[2];   // [1024,1024]
    float* out = (float*)d_out;                  // [4,2048,1024] fp32

    unsigned short* qb  = (unsigned short*)d_ws;          //  16.8 MB (pre-scaled Q)
    unsigned short* kb  = qb + 8388608;                   //  16.8 MB
    unsigned short* vbt = kb + 8388608;                   //  16.8 MB (V transposed)
    unsigned short* drp = vbt + 8388608;                  //  33.5 MB (1/denom, tiled C-layout)
    unsigned short* cb  = drp + 16777216;                 //  16.8 MB (concat)
    // total = 100,663,296 bytes

    qkv_gemm  <<<dim3(24, 64),    256, 0, stream>>>(x, wqkv, qb, kb, vbt);
    attn_denom<<<dim3(64, 64, 4), 256, 0, stream>>>(qb, kb, drp);
    attn_pv   <<<dim3(32, 16, 4), 256, 0, stream>>>(qb, kb, vbt, drp, cb);
    out_gemm  <<<dim3(8, 64),     256, 0, stream>>>(cb, wo, out);
}

// Round 3
// 518.827 us; speedup vs baseline: 2.2103x; 2.2103x over previous
//
#include <hip/hip_runtime.h>
#include <hip/hip_bf16.h>
#include <stdint.h>

typedef __attribute__((ext_vector_type(8))) short short8;
typedef __attribute__((ext_vector_type(4))) float floatx4;

// Q pre-scale: 0.125 (1/sqrt(K)) * log2(e), so exp(s/8) == exp2(q'.k)
#define QSCALE 0.18033688f

__device__ __forceinline__ unsigned short f2bf(float f) {
    unsigned int u = __float_as_uint(f);
    u += 0x7fffu + ((u >> 16) & 1u);
    return (unsigned short)(u >> 16);
}
__device__ __forceinline__ unsigned int pack2bf(float a, float b) {
    __hip_bfloat162 h = __float22bfloat162_rn(make_float2(a, b));
    return *reinterpret_cast<unsigned int*>(&h);
}

// ---------------------------------------------------------------------------
// cvt: fp32 -> bf16, 8 elements/thread
// ---------------------------------------------------------------------------
__global__ __launch_bounds__(256) void cvt_bf16(const float* __restrict__ src,
                                                unsigned short* __restrict__ dst, int n8) {
    int i = blockIdx.x * 256 + threadIdx.x;
    if (i >= n8) return;
    const float4 a = ((const float4*)src)[2 * i];
    const float4 b = ((const float4*)src)[2 * i + 1];
    ushort4 lo, hi;
    lo.x = f2bf(a.x); lo.y = f2bf(a.y); lo.z = f2bf(a.z); lo.w = f2bf(a.w);
    hi.x = f2bf(b.x); hi.y = f2bf(b.y); hi.z = f2bf(b.z); hi.w = f2bf(b.w);
    ((ushort4*)dst)[2 * i] = lo;
    ((ushort4*)dst)[2 * i + 1] = hi;
}

// ---------------------------------------------------------------------------
// tcvt: fp32 [R][C] -> bf16 [C][R]  (64x64 tiles via LDS)
// ---------------------------------------------------------------------------
__global__ __launch_bounds__(256) void tcvt(const float* __restrict__ src,
                                            unsigned short* __restrict__ dst, int R, int C) {
    __shared__ unsigned short t[64][72];
    const int tid = threadIdx.x;
    const int r0 = blockIdx.y * 64, c0 = blockIdx.x * 64;
    #pragma unroll
    for (int it = 0; it < 4; it++) {
        int idx = it * 256 + tid;
        int rr = idx >> 4, cc = (idx & 15) * 4;
        float4 v = *(const float4*)(src + (size_t)(r0 + rr) * C + c0 + cc);
        t[cc + 0][rr] = f2bf(v.x);
        t[cc + 1][rr] = f2bf(v.y);
        t[cc + 2][rr] = f2bf(v.z);
        t[cc + 3][rr] = f2bf(v.w);
    }
    __syncthreads();
    #pragma unroll
    for (int it = 0; it < 2; it++) {
        int idx = it * 256 + tid;
        int cc = idx >> 3, r8 = (idx & 7) * 8;
        short8 v = *(const short8*)&t[cc][r8];
        *(short8*)(dst + (size_t)(c0 + cc) * R + r0 + r8) = v;
    }
}

// ---------------------------------------------------------------------------
// vtrans: vb[bh][2048][64] -> vbt[bh][64][2048]  (64x64 tiles via LDS)
// ---------------------------------------------------------------------------
__global__ __launch_bounds__(256) void vtrans(const unsigned short* __restrict__ vb,
                                              unsigned short* __restrict__ vbt) {
    __shared__ unsigned short t[64][72];
    const int tid = threadIdx.x;
    const int bh = blockIdx.y, m0 = blockIdx.x * 64;
    const unsigned short* src = vb + ((size_t)bh * 2048 + m0) * 64;
    unsigned short* dst = vbt + ((size_t)bh << 17) + m0;
    union { short8 v; unsigned short u[8]; } tmp;
    #pragma unroll
    for (int it = 0; it < 2; it++) {
        int idx = it * 256 + tid;
        int m = idx >> 3, c8 = (idx & 7) * 8;
        tmp.v = *(const short8*)(src + (size_t)m * 64 + c8);
        #pragma unroll
        for (int j = 0; j < 8; j++) t[c8 + j][m] = tmp.u[j];
    }
    __syncthreads();
    #pragma unroll
    for (int it = 0; it < 2; it++) {
        int idx = it * 256 + tid;
        int k = idx >> 3, c8 = (idx & 7) * 8;
        short8 v = *(const short8*)&t[k][c8];
        *(short8*)(dst + (size_t)k * 2048 + c8) = v;
    }
}

// ---------------------------------------------------------------------------
// GEMM core (m93-style 128x128 tile, BK=32), A [M][1024] bf16, Bt [N][1024] bf16
// Used by qkv_gemm (epilogue scatters q/k/v) and out_gemm (fp32 C).
// ---------------------------------------------------------------------------
__global__ __launch_bounds__(256) void qkv_gemm(
    const unsigned short* __restrict__ A, const unsigned short* __restrict__ Bt,
    unsigned short* __restrict__ qb, unsigned short* __restrict__ kb,
    unsigned short* __restrict__ vb)
{
    __shared__ __align__(16) unsigned short As[128 * 32];
    __shared__ __align__(16) unsigned short Bs[128 * 32];
    const int tid = threadIdx.x, wave = tid >> 6, lane = tid & 63;
    const int quad = lane >> 4, lr = lane & 15;
    const int wr = wave >> 1, wc = wave & 1;
    const int bm = blockIdx.y * 128, bn = blockIdx.x * 128;
    const int srow = wave * 32 + (lane >> 2);
    const int sblk = lane & 3;

    floatx4 acc[4][4];
    #pragma unroll
    for (int i = 0; i < 4; i++)
        #pragma unroll
        for (int j = 0; j < 4; j++) acc[i][j] = (floatx4)0.0f;

    for (int k0 = 0; k0 < 1024; k0 += 32) {
        #pragma unroll
        for (int t = 0; t < 2; t++) {
            int r = srow + t * 16;
            short8 va = *(const short8*)(A  + (size_t)(bm + r) * 1024 + k0 + sblk * 8);
            short8 vw = *(const short8*)(Bt + (size_t)(bn + r) * 1024 + k0 + sblk * 8);
            *(short8*)&As[r * 32 + sblk * 8] = va;
            *(short8*)&Bs[r * 32 + sblk * 8] = vw;
        }
        __syncthreads();
        short8 af[4], bfr[4];
        #pragma unroll
        for (int i = 0; i < 4; i++)
            af[i] = *(const short8*)&As[(wr * 64 + i * 16 + lr) * 32 + quad * 8];
        #pragma unroll
        for (int j = 0; j < 4; j++)
            bfr[j] = *(const short8*)&Bs[(wc * 64 + j * 16 + lr) * 32 + quad * 8];
        #pragma unroll
        for (int i = 0; i < 4; i++)
            #pragma unroll
            for (int j = 0; j < 4; j++)
                acc[i][j] = __builtin_amdgcn_mfma_f32_16x16x32_bf16(af[i], bfr[j], acc[i][j], 0, 0, 0);
        __syncthreads();
    }

    const int part = bn >> 10;
    unsigned short* __restrict__ dstb = (part == 0) ? qb : ((part == 1) ? kb : vb);
    const float sc = (part == 0) ? QSCALE : 1.0f;
    const int dbase = bn & 1023;
    #pragma unroll
    for (int i = 0; i < 4; i++)
        #pragma unroll
        for (int j = 0; j < 4; j++)
            #pragma unroll
            for (int r = 0; r < 4; r++) {
                int row = bm + wr * 64 + i * 16 + quad * 4 + r;
                int d   = dbase + wc * 64 + j * 16 + lr;
                int b = row >> 11, l = row & 2047;
                int flat = (l << 10) | d;
                int h = flat >> 17;
                int rem = flat & 131071;
                int l2 = rem >> 6, kk = rem & 63;
                dstb[((size_t)(b * 16 + h) * 2048 + l2) * 64 + kk] = f2bf(acc[i][j][r] * sc);
            }
}

__global__ __launch_bounds__(256) void out_gemm(
    const unsigned short* __restrict__ A, const unsigned short* __restrict__ Bt,
    float* __restrict__ C)
{
    __shared__ __align__(16) unsigned short As[128 * 32];
    __shared__ __align__(16) unsigned short Bs[128 * 32];
    const int tid = threadIdx.x, wave = tid >> 6, lane = tid & 63;
    const int quad = lane >> 4, lr = lane & 15;
    const int wr = wave >> 1, wc = wave & 1;
    const int bm = blockIdx.y * 128, bn = blockIdx.x * 128;
    const int srow = wave * 32 + (lane >> 2);
    const int sblk = lane & 3;

    floatx4 acc[4][4];
    #pragma unroll
    for (int i = 0; i < 4; i++)
        #pragma unroll
        for (int j = 0; j < 4; j++) acc[i][j] = (floatx4)0.0f;

    for (int k0 = 0; k0 < 1024; k0 += 32) {
        #pragma unroll
        for (int t = 0; t < 2; t++) {
            int r = srow + t * 16;
            short8 va = *(const short8*)(A  + (size_t)(bm + r) * 1024 + k0 + sblk * 8);
            short8 vw = *(const short8*)(Bt + (size_t)(bn + r) * 1024 + k0 + sblk * 8);
            *(short8*)&As[r * 32 + sblk * 8] = va;
            *(short8*)&Bs[r * 32 + sblk * 8] = vw;
        }
        __syncthreads();
        short8 af[4], bfr[4];
        #pragma unroll
        for (int i = 0; i < 4; i++)
            af[i] = *(const short8*)&As[(wr * 64 + i * 16 + lr) * 32 + quad * 8];
        #pragma unroll
        for (int j = 0; j < 4; j++)
            bfr[j] = *(const short8*)&Bs[(wc * 64 + j * 16 + lr) * 32 + quad * 8];
        #pragma unroll
        for (int i = 0; i < 4; i++)
            #pragma unroll
            for (int j = 0; j < 4; j++)
                acc[i][j] = __builtin_amdgcn_mfma_f32_16x16x32_bf16(af[i], bfr[j], acc[i][j], 0, 0, 0);
        __syncthreads();
    }
    #pragma unroll
    for (int i = 0; i < 4; i++)
        #pragma unroll
        for (int j = 0; j < 4; j++)
            #pragma unroll
            for (int r = 0; r < 4; r++) {
                int row = bm + wr * 64 + i * 16 + quad * 4 + r;
                int col = bn + wc * 64 + j * 16 + lr;
                C[(size_t)row * 1024 + col] = acc[i][j][r];
            }
}

// ---------------------------------------------------------------------------
// attn_denom: block = (b, 128 l x 128 m). Loops 16 heads, staging Q/K tiles
// in swizzled LDS, computes S^T = K.Q^T (D[m][l]), accumulates exp2.
// Stores reciprocal denom in transposed-C-tile order: drpT[b][mt][lt] tile of
// 256 u16, element (m=quad*4+r, l=lr) at lane*4+r  (coalesced uint2/lane).
// ---------------------------------------------------------------------------
__global__ __launch_bounds__(256) void attn_denom(
    const unsigned short* __restrict__ qb, const unsigned short* __restrict__ kb,
    unsigned short* __restrict__ drpT)
{
    __shared__ __align__(16) unsigned short Qs[128 * 64];
    __shared__ __align__(16) unsigned short Ks[128 * 64];
    const int tid = threadIdx.x, wave = tid >> 6, lane = tid & 63;
    const int quad = lane >> 4, lr = lane & 15;
    const int wm = wave >> 1, wl = wave & 1;
    const int M0 = blockIdx.x * 128, L0 = blockIdx.y * 128, b = blockIdx.z;
    const int srow8 = lane >> 3;   // 0..7
    const int sblk = lane & 7;     // 0..7 (16B blocks within 128B row)

    floatx4 e[4][4];
    #pragma unroll
    for (int i = 0; i < 4; i++)
        #pragma unroll
        for (int j = 0; j < 4; j++) e[i][j] = (floatx4)0.0f;

    for (int h = 0; h < 16; h++) {
        const size_t hb = ((size_t)(b * 16 + h)) << 17;   // * 2048*64
        #pragma unroll
        for (int t = 0; t < 4; t++) {
            int rl = wave * 32 + t * 8 + srow8;
            int phys = sblk ^ (rl & 7);
            short8 vq = *(const short8*)(qb + hb + (size_t)(L0 + rl) * 64 + sblk * 8);
            short8 vk = *(const short8*)(kb + hb + (size_t)(M0 + rl) * 64 + sblk * 8);
            *(short8*)&Qs[rl * 64 + phys * 8] = vq;
            *(short8*)&Ks[rl * 64 + phys * 8] = vk;
        }
        __syncthreads();
        short8 qf[4][2];
        #pragma unroll
        for (int j = 0; j < 4; j++) {
            int rq = wl * 64 + j * 16 + lr;
            qf[j][0] = *(const short8*)&Qs[rq * 64 + (quad ^ (lr & 7)) * 8];
            qf[j][1] = *(const short8*)&Qs[rq * 64 + ((4 + quad) ^ (lr & 7)) * 8];
        }
        #pragma unroll
        for (int i = 0; i < 4; i++) {
            int rk = wm * 64 + i * 16 + lr;
            short8 kf0 = *(const short8*)&Ks[rk * 64 + (quad ^ (lr & 7)) * 8];
            short8 kf1 = *(const short8*)&Ks[rk * 64 + ((4 + quad) ^ (lr & 7)) * 8];
            #pragma unroll
            for (int j = 0; j < 4; j++) {
                floatx4 s = (floatx4)0.0f;
                s = __builtin_amdgcn_mfma_f32_16x16x32_bf16(kf0, qf[j][0], s, 0, 0, 0);
                s = __builtin_amdgcn_mfma_f32_16x16x32_bf16(kf1, qf[j][1], s, 0, 0, 0);
                e[i][j][0] += __builtin_amdgcn_exp2f(s[0]);
                e[i][j][1] += __builtin_amdgcn_exp2f(s[1]);
                e[i][j][2] += __builtin_amdgcn_exp2f(s[2]);
                e[i][j][3] += __builtin_amdgcn_exp2f(s[3]);
            }
        }
        __syncthreads();
    }
    #pragma unroll
    for (int i = 0; i < 4; i++)
        #pragma unroll
        for (int j = 0; j < 4; j++) {
            float r0 = __builtin_amdgcn_rcpf(e[i][j][0]);
            float r1 = __builtin_amdgcn_rcpf(e[i][j][1]);
            float r2 = __builtin_amdgcn_rcpf(e[i][j][2]);
            float r3 = __builtin_amdgcn_rcpf(e[i][j][3]);
            uint2 o;
            o.x = pack2bf(r0, r1);
            o.y = pack2bf(r2, r3);
            int mt = (M0 >> 4) + wm * 4 + i;
            int lt = (L0 >> 4) + wl * 4 + j;
            *(uint2*)(drpT + ((((size_t)b * 128 + mt) * 128 + lt) << 8) + lane * 4) = o;
        }
}

// ---------------------------------------------------------------------------
// attn_pv: block = (b, h, 128 l-rows). Per 128-m tile: stage K in swizzled LDS,
// S^T = K.Q^T (Q frags in registers), P = exp2(S)*drpT (coalesced), P written
// m-contiguous (b64) into swizzled LDS; PV reads P as A-frags (b128) and V^T
// B-frags direct from global. 2 barriers per m-tile.
// ---------------------------------------------------------------------------
__global__ __launch_bounds__(256) void attn_pv(
    const unsigned short* __restrict__ qb, const unsigned short* __restrict__ kb,
    const unsigned short* __restrict__ vbt, const unsigned short* __restrict__ drpT,
    unsigned short* __restrict__ cb)
{
    __shared__ __align__(16) unsigned short Ks[128 * 64];   // 16 KB
    __shared__ __align__(16) unsigned short Ps[128 * 128];  // 32 KB
    const int tid = threadIdx.x, wave = tid >> 6, lane = tid & 63;
    const int quad = lane >> 4, lr = lane & 15;
    const int wm = wave >> 1, wl = wave & 1;   // S roles (m-half, l-half)
    const int L0 = blockIdx.x * 128, h = blockIdx.y, b = blockIdx.z;
    const size_t head = (size_t)(b * 16 + h);
    const unsigned short* qbase = qb + (head << 17);
    const unsigned short* kbase = kb + (head << 17);
    const unsigned short* vtb   = vbt + (head << 17);       // [64][2048]
    const int srow8 = lane >> 3, sblk = lane & 7;

    // Q B-fragments in registers (rows l = L0 + wl*64 + j*16 + lr)
    short8 qf[4][2];
    #pragma unroll
    for (int j = 0; j < 4; j++) {
        const unsigned short* qr = qbase + (size_t)(L0 + wl * 64 + j * 16 + lr) * 64;
        qf[j][0] = *(const short8*)(qr + quad * 8);
        qf[j][1] = *(const short8*)(qr + 32 + quad * 8);
    }

    floatx4 oacc[4][2];
    #pragma unroll
    for (int i = 0; i < 4; i++)
        #pragma unroll
        for (int j = 0; j < 2; j++) oacc[i][j] = (floatx4)0.0f;

    for (int M0 = 0; M0 < 2048; M0 += 128) {
        // ---- stage K tile [128][64] swizzled ----
        #pragma unroll
        for (int t = 0; t < 4; t++) {
            int rl = wave * 32 + t * 8 + srow8;
            int phys = sblk ^ (rl & 7);
            short8 vk = *(const short8*)(kbase + (size_t)(M0 + rl) * 64 + sblk * 8);
            *(short8*)&Ks[rl * 64 + phys * 8] = vk;
        }
        __syncthreads();
        // ---- S^T = K.Q^T, P = exp2*drp, write to Ps ----
        #pragma unroll
        for (int i = 0; i < 4; i++) {
            int rk = wm * 64 + i * 16 + lr;
            short8 kf0 = *(const short8*)&Ks[rk * 64 + (quad ^ (lr & 7)) * 8];
            short8 kf1 = *(const short8*)&Ks[rk * 64 + ((4 + quad) ^ (lr & 7)) * 8];
            int mt = (M0 >> 4) + wm * 4 + i;
            #pragma unroll
            for (int j = 0; j < 4; j++) {
                int lt = (L0 >> 4) + wl * 4 + j;
                uint2 du = *(const uint2*)(drpT + ((((size_t)b * 128 + mt) * 128 + lt) << 8) + lane * 4);
                floatx4 s = (floatx4)0.0f;
                s = __builtin_amdgcn_mfma_f32_16x16x32_bf16(kf0, qf[j][0], s, 0, 0, 0);
                s = __builtin_amdgcn_mfma_f32_16x16x32_bf16(kf1, qf[j][1], s, 0, 0, 0);
                float r0 = __uint_as_float(du.x << 16);
                float r1 = __uint_as_float(du.x & 0xffff0000u);
                float r2 = __uint_as_float(du.y << 16);
                float r3 = __uint_as_float(du.y & 0xffff0000u);
                float p0 = __builtin_amdgcn_exp2f(s[0]) * r0;
                float p1 = __builtin_amdgcn_exp2f(s[1]) * r1;
                float p2 = __builtin_amdgcn_exp2f(s[2]) * r2;
                float p3 = __builtin_amdgcn_exp2f(s[3]) * r3;
                uint2 o;
                o.x = pack2bf(p0, p1);
                o.y = pack2bf(p2, p3);
                int l_loc = wl * 64 + j * 16 + lr;
                int m_blk = wm * 8 + i * 2 + (quad >> 1);
                int phys = m_blk ^ (l_loc & 7);
                *(uint2*)&Ps[l_loc * 128 + phys * 8 + (quad & 1) * 4] = o;
            }
        }
        __syncthreads();
        // ---- O += P @ V  (P A-frags from LDS, V^T B-frags from global) ----
        #pragma unroll
        for (int ks = 0; ks < 4; ks++) {
            short8 pf[4];
            #pragma unroll
            for (int i2 = 0; i2 < 4; i2++) {
                int lrow = wm * 64 + i2 * 16 + lr;   // reuse wm as l-half for PV
                int pb = (ks * 4 + quad) ^ (lrow & 7);
                pf[i2] = *(const short8*)&Ps[lrow * 128 + pb * 8];
            }
            #pragma unroll
            for (int j2 = 0; j2 < 2; j2++) {
                int nrow = wl * 32 + j2 * 16 + lr;   // reuse wl as n-half for PV
                short8 vf = *(const short8*)(vtb + (size_t)nrow * 2048 + M0 + ks * 32 + quad * 8);
                #pragma unroll
                for (int i2 = 0; i2 < 4; i2++)
                    oacc[i2][j2] = __builtin_amdgcn_mfma_f32_16x16x32_bf16(pf[i2], vf, oacc[i2][j2], 0, 0, 0);
            }
        }
    }
    // epilogue: concat layout cb[b*2048 + l][h*64 + n]
    #pragma unroll
    for (int i2 = 0; i2 < 4; i2++)
        #pragma unroll
        for (int j2 = 0; j2 < 2; j2++)
            #pragma unroll
            for (int r = 0; r < 4; r++) {
                int row = L0 + wm * 64 + i2 * 16 + quad * 4 + r;
                int col = h * 64 + wl * 32 + j2 * 16 + lr;
                cb[(size_t)(b * 2048 + row) * 1024 + col] = f2bf(oacc[i2][j2][r]);
            }
}

extern "C" void kernel_launch(void* const* d_in, const int* in_sizes, int n_in,
                              void* d_out, int out_size, void* d_ws, size_t ws_size,
                              hipStream_t stream) {
    const float* x    = (const float*)d_in[0];   // [4,2048,1024]
    const float* wqkv = (const float*)d_in[1];   // [1024,3072]
    const float* wo   = (const float*)d_in[2];   // [1024,1024]
    float* out = (float*)d_out;                  // [4,2048,1024] fp32

    // workspace: 50,331,648 u16 elements = 100,663,296 bytes, with overlays
    unsigned short* W = (unsigned short*)d_ws;
    unsigned short* qb   = W;                    // [4,16,2048,64] pre-scaled Q
    unsigned short* kb   = W + 8388608;          // [4,16,2048,64]
    unsigned short* vbt  = W + 16777216;         // [4,16,64,2048] V^T
    unsigned short* drpT = W + 25165824;         // [4][128mt][128lt][256] recip denom
    unsigned short* cb   = W + 41943040;         // [8192,1024] concat
    // overlays (lifetime-disjoint):
    unsigned short* xb    = drpT;                // bf16 x   (dead before denom)
    unsigned short* wqkvT = drpT + 8388608;      // bf16 wqkv^T [3072][1024]
    unsigned short* vb    = cb;                  // V row-major (dead before pv)
    unsigned short* woT   = drpT;                // bf16 wo^T [1024][1024] (after pv)

    cvt_bf16  <<<4096, 256, 0, stream>>>(x, xb, 1048576);
    tcvt      <<<dim3(48, 16), 256, 0, stream>>>(wqkv, wqkvT, 1024, 3072);
    qkv_gemm  <<<dim3(24, 64), 256, 0, stream>>>(xb, wqkvT, qb, kb, vb);
    vtrans    <<<dim3(32, 64), 256, 0, stream>>>(vb, vbt);
    attn_denom<<<dim3(16, 16, 4), 256, 0, stream>>>(qb, kb, drpT);
    attn_pv   <<<dim3(16, 16, 4), 256, 0, stream>>>(qb, kb, vbt, drpT, cb);
    tcvt      <<<dim3(16, 16), 256, 0, stream>>>(wo, woT, 1024, 1024);
    out_gemm  <<<dim3(8, 64), 256, 0, stream>>>(cb, woT, out);
}

// Round 4
// 428.118 us; speedup vs baseline: 2.6786x; 1.2119x over previous
//
#include <hip/hip_runtime.h>
#include <hip/hip_bf16.h>
#include <stdint.h>

typedef __attribute__((ext_vector_type(8))) short short8;
typedef __attribute__((ext_vector_type(4))) float floatx4;

// Q pre-scale: 0.125 (1/sqrt(K)) * log2(e), so exp(s/8) == exp2(q'.k)
#define QSCALE 0.18033688f

__device__ __forceinline__ unsigned short f2bf(float f) {
    unsigned int u = __float_as_uint(f);
    u += 0x7fffu + ((u >> 16) & 1u);
    return (unsigned short)(u >> 16);
}
__device__ __forceinline__ unsigned int pack2bf(float a, float b) {
    __hip_bfloat162 h = __float22bfloat162_rn(make_float2(a, b));
    return *reinterpret_cast<unsigned int*>(&h);
}

// ---------------------------------------------------------------------------
// cvt: fp32 -> bf16, 8 elements/thread
// ---------------------------------------------------------------------------
__global__ __launch_bounds__(256) void cvt_bf16(const float* __restrict__ src,
                                                unsigned short* __restrict__ dst, int n8) {
    int i = blockIdx.x * 256 + threadIdx.x;
    if (i >= n8) return;
    const float4 a = ((const float4*)src)[2 * i];
    const float4 b = ((const float4*)src)[2 * i + 1];
    ushort4 lo, hi;
    lo.x = f2bf(a.x); lo.y = f2bf(a.y); lo.z = f2bf(a.z); lo.w = f2bf(a.w);
    hi.x = f2bf(b.x); hi.y = f2bf(b.y); hi.z = f2bf(b.z); hi.w = f2bf(b.w);
    ((ushort4*)dst)[2 * i] = lo;
    ((ushort4*)dst)[2 * i + 1] = hi;
}

// ---------------------------------------------------------------------------
// tcvt: fp32 [R][C] -> bf16 [C][R]  (64x64 tiles via LDS)
// ---------------------------------------------------------------------------
__global__ __launch_bounds__(256) void tcvt(const float* __restrict__ src,
                                            unsigned short* __restrict__ dst, int R, int C) {
    __shared__ unsigned short t[64][72];
    const int tid = threadIdx.x;
    const int r0 = blockIdx.y * 64, c0 = blockIdx.x * 64;
    #pragma unroll
    for (int it = 0; it < 4; it++) {
        int idx = it * 256 + tid;
        int rr = idx >> 4, cc = (idx & 15) * 4;
        float4 v = *(const float4*)(src + (size_t)(r0 + rr) * C + c0 + cc);
        t[cc + 0][rr] = f2bf(v.x);
        t[cc + 1][rr] = f2bf(v.y);
        t[cc + 2][rr] = f2bf(v.z);
        t[cc + 3][rr] = f2bf(v.w);
    }
    __syncthreads();
    #pragma unroll
    for (int it = 0; it < 2; it++) {
        int idx = it * 256 + tid;
        int cc = idx >> 3, r8 = (idx & 7) * 8;
        short8 v = *(const short8*)&t[cc][r8];
        *(short8*)(dst + (size_t)(c0 + cc) * R + r0 + r8) = v;
    }
}

// ---------------------------------------------------------------------------
// vtrans: vb[bh][2048][64] -> vbt[bh][64][2048]  (64x64 tiles via LDS)
// ---------------------------------------------------------------------------
__global__ __launch_bounds__(256) void vtrans(const unsigned short* __restrict__ vb,
                                              unsigned short* __restrict__ vbt) {
    __shared__ unsigned short t[64][72];
    const int tid = threadIdx.x;
    const int bh = blockIdx.y, m0 = blockIdx.x * 64;
    const unsigned short* src = vb + ((size_t)bh * 2048 + m0) * 64;
    unsigned short* dst = vbt + ((size_t)bh << 17) + m0;
    union { short8 v; unsigned short u[8]; } tmp;
    #pragma unroll
    for (int it = 0; it < 2; it++) {
        int idx = it * 256 + tid;
        int m = idx >> 3, c8 = (idx & 7) * 8;
        tmp.v = *(const short8*)(src + (size_t)m * 64 + c8);
        #pragma unroll
        for (int j = 0; j < 8; j++) t[c8 + j][m] = tmp.u[j];
    }
    __syncthreads();
    #pragma unroll
    for (int it = 0; it < 2; it++) {
        int idx = it * 256 + tid;
        int k = idx >> 3, c8 = (idx & 7) * 8;
        short8 v = *(const short8*)&t[k][c8];
        *(short8*)(dst + (size_t)k * 2048 + c8) = v;
    }
}

// ---------------------------------------------------------------------------
// qkv_gemm (m93-style 128x128 tile, BK=32), epilogue scatters q/k/v
// ---------------------------------------------------------------------------
__global__ __launch_bounds__(256) void qkv_gemm(
    const unsigned short* __restrict__ A, const unsigned short* __restrict__ Bt,
    unsigned short* __restrict__ qb, unsigned short* __restrict__ kb,
    unsigned short* __restrict__ vb)
{
    __shared__ __align__(16) unsigned short As[128 * 32];
    __shared__ __align__(16) unsigned short Bs[128 * 32];
    const int tid = threadIdx.x, wave = tid >> 6, lane = tid & 63;
    const int quad = lane >> 4, lr = lane & 15;
    const int wr = wave >> 1, wc = wave & 1;
    const int bm = blockIdx.y * 128, bn = blockIdx.x * 128;
    const int srow = wave * 32 + (lane >> 2);
    const int sblk = lane & 3;

    floatx4 acc[4][4];
    #pragma unroll
    for (int i = 0; i < 4; i++)
        #pragma unroll
        for (int j = 0; j < 4; j++) acc[i][j] = (floatx4)0.0f;

    for (int k0 = 0; k0 < 1024; k0 += 32) {
        #pragma unroll
        for (int t = 0; t < 2; t++) {
            int r = srow + t * 16;
            short8 va = *(const short8*)(A  + (size_t)(bm + r) * 1024 + k0 + sblk * 8);
            short8 vw = *(const short8*)(Bt + (size_t)(bn + r) * 1024 + k0 + sblk * 8);
            *(short8*)&As[r * 32 + sblk * 8] = va;
            *(short8*)&Bs[r * 32 + sblk * 8] = vw;
        }
        __syncthreads();
        short8 af[4], bfr[4];
        #pragma unroll
        for (int i = 0; i < 4; i++)
            af[i] = *(const short8*)&As[(wr * 64 + i * 16 + lr) * 32 + quad * 8];
        #pragma unroll
        for (int j = 0; j < 4; j++)
            bfr[j] = *(const short8*)&Bs[(wc * 64 + j * 16 + lr) * 32 + quad * 8];
        #pragma unroll
        for (int i = 0; i < 4; i++)
            #pragma unroll
            for (int j = 0; j < 4; j++)
                acc[i][j] = __builtin_amdgcn_mfma_f32_16x16x32_bf16(af[i], bfr[j], acc[i][j], 0, 0, 0);
        __syncthreads();
    }

    const int part = bn >> 10;
    unsigned short* __restrict__ dstb = (part == 0) ? qb : ((part == 1) ? kb : vb);
    const float sc = (part == 0) ? QSCALE : 1.0f;
    const int dbase = bn & 1023;
    #pragma unroll
    for (int i = 0; i < 4; i++)
        #pragma unroll
        for (int j = 0; j < 4; j++)
            #pragma unroll
            for (int r = 0; r < 4; r++) {
                int row = bm + wr * 64 + i * 16 + quad * 4 + r;
                int d   = dbase + wc * 64 + j * 16 + lr;
                int b = row >> 11, l = row & 2047;
                int flat = (l << 10) | d;
                int h = flat >> 17;
                int rem = flat & 131071;
                int l2 = rem >> 6, kk = rem & 63;
                dstb[((size_t)(b * 16 + h) * 2048 + l2) * 64 + kk] = f2bf(acc[i][j][r] * sc);
            }
}

__global__ __launch_bounds__(256) void out_gemm(
    const unsigned short* __restrict__ A, const unsigned short* __restrict__ Bt,
    float* __restrict__ C)
{
    __shared__ __align__(16) unsigned short As[128 * 32];
    __shared__ __align__(16) unsigned short Bs[128 * 32];
    const int tid = threadIdx.x, wave = tid >> 6, lane = tid & 63;
    const int quad = lane >> 4, lr = lane & 15;
    const int wr = wave >> 1, wc = wave & 1;
    const int bm = blockIdx.y * 128, bn = blockIdx.x * 128;
    const int srow = wave * 32 + (lane >> 2);
    const int sblk = lane & 3;

    floatx4 acc[4][4];
    #pragma unroll
    for (int i = 0; i < 4; i++)
        #pragma unroll
        for (int j = 0; j < 4; j++) acc[i][j] = (floatx4)0.0f;

    for (int k0 = 0; k0 < 1024; k0 += 32) {
        #pragma unroll
        for (int t = 0; t < 2; t++) {
            int r = srow + t * 16;
            short8 va = *(const short8*)(A  + (size_t)(bm + r) * 1024 + k0 + sblk * 8);
            short8 vw = *(const short8*)(Bt + (size_t)(bn + r) * 1024 + k0 + sblk * 8);
            *(short8*)&As[r * 32 + sblk * 8] = va;
            *(short8*)&Bs[r * 32 + sblk * 8] = vw;
        }
        __syncthreads();
        short8 af[4], bfr[4];
        #pragma unroll
        for (int i = 0; i < 4; i++)
            af[i] = *(const short8*)&As[(wr * 64 + i * 16 + lr) * 32 + quad * 8];
        #pragma unroll
        for (int j = 0; j < 4; j++)
            bfr[j] = *(const short8*)&Bs[(wc * 64 + j * 16 + lr) * 32 + quad * 8];
        #pragma unroll
        for (int i = 0; i < 4; i++)
            #pragma unroll
            for (int j = 0; j < 4; j++)
                acc[i][j] = __builtin_amdgcn_mfma_f32_16x16x32_bf16(af[i], bfr[j], acc[i][j], 0, 0, 0);
        __syncthreads();
    }
    #pragma unroll
    for (int i = 0; i < 4; i++)
        #pragma unroll
        for (int j = 0; j < 4; j++)
            #pragma unroll
            for (int r = 0; r < 4; r++) {
                int row = bm + wr * 64 + i * 16 + quad * 4 + r;
                int col = bn + wc * 64 + j * 16 + lr;
                C[(size_t)row * 1024 + col] = acc[i][j][r];
            }
}

// ---------------------------------------------------------------------------
// attn_denom: block = (b, 64 l x 64 m). Loops 16 heads; Q/K tiles (8 KB each)
// staged swizzled in LDS; next head's tiles prefetched into registers during
// compute. Wave w owns l-strip w (16 rows) x all 4 m-tiles. Stores reciprocal
// denom in transposed-C-tile order drpT[b][mt][lt][256].
// ---------------------------------------------------------------------------
__global__ __launch_bounds__(256, 4) void attn_denom(
    const unsigned short* __restrict__ qb, const unsigned short* __restrict__ kb,
    unsigned short* __restrict__ drpT)
{
    __shared__ __align__(16) unsigned short Qs[64 * 64];
    __shared__ __align__(16) unsigned short Ks[64 * 64];
    const int tid = threadIdx.x, wave = tid >> 6, lane = tid & 63;
    const int quad = lane >> 4, lr = lane & 15;
    const int M0 = blockIdx.x * 64, L0 = blockIdx.y * 64, b = blockIdx.z;
    const int srow = tid >> 3, sblk = tid & 7;       // rows srow, srow+32
    const int sphys = (sblk ^ (srow & 7)) * 8;

    floatx4 e[4];
    #pragma unroll
    for (int i = 0; i < 4; i++) e[i] = (floatx4)0.0f;

    // prologue: stage head 0
    {
        const size_t hb = ((size_t)(b * 16)) << 17;
        short8 q0 = *(const short8*)(qb + hb + (size_t)(L0 + srow) * 64 + sblk * 8);
        short8 q1 = *(const short8*)(qb + hb + (size_t)(L0 + srow + 32) * 64 + sblk * 8);
        short8 k0 = *(const short8*)(kb + hb + (size_t)(M0 + srow) * 64 + sblk * 8);
        short8 k1 = *(const short8*)(kb + hb + (size_t)(M0 + srow + 32) * 64 + sblk * 8);
        *(short8*)&Qs[srow * 64 + sphys] = q0;
        *(short8*)&Qs[(srow + 32) * 64 + sphys] = q1;
        *(short8*)&Ks[srow * 64 + sphys] = k0;
        *(short8*)&Ks[(srow + 32) * 64 + sphys] = k1;
    }
    __syncthreads();

    for (int h = 0; h < 16; h++) {
        short8 qn0, qn1, kn0, kn1;
        if (h < 15) {
            const size_t hb = ((size_t)(b * 16 + h + 1)) << 17;
            qn0 = *(const short8*)(qb + hb + (size_t)(L0 + srow) * 64 + sblk * 8);
            qn1 = *(const short8*)(qb + hb + (size_t)(L0 + srow + 32) * 64 + sblk * 8);
            kn0 = *(const short8*)(kb + hb + (size_t)(M0 + srow) * 64 + sblk * 8);
            kn1 = *(const short8*)(kb + hb + (size_t)(M0 + srow + 32) * 64 + sblk * 8);
        }
        // compute: wave owns l-tile = wave
        const int rq = wave * 16 + lr;
        short8 qf0 = *(const short8*)&Qs[rq * 64 + ((quad) ^ (lr & 7)) * 8];
        short8 qf1 = *(const short8*)&Qs[rq * 64 + ((4 + quad) ^ (lr & 7)) * 8];
        #pragma unroll
        for (int mt = 0; mt < 4; mt++) {
            const int rk = mt * 16 + lr;
            short8 kf0 = *(const short8*)&Ks[rk * 64 + ((quad) ^ (lr & 7)) * 8];
            short8 kf1 = *(const short8*)&Ks[rk * 64 + ((4 + quad) ^ (lr & 7)) * 8];
            floatx4 s = (floatx4)0.0f;
            s = __builtin_amdgcn_mfma_f32_16x16x32_bf16(kf0, qf0, s, 0, 0, 0);
            s = __builtin_amdgcn_mfma_f32_16x16x32_bf16(kf1, qf1, s, 0, 0, 0);
            e[mt][0] += __builtin_amdgcn_exp2f(s[0]);
            e[mt][1] += __builtin_amdgcn_exp2f(s[1]);
            e[mt][2] += __builtin_amdgcn_exp2f(s[2]);
            e[mt][3] += __builtin_amdgcn_exp2f(s[3]);
        }
        __syncthreads();
        if (h < 15) {
            *(short8*)&Qs[srow * 64 + sphys] = qn0;
            *(short8*)&Qs[(srow + 32) * 64 + sphys] = qn1;
            *(short8*)&Ks[srow * 64 + sphys] = kn0;
            *(short8*)&Ks[(srow + 32) * 64 + sphys] = kn1;
            __syncthreads();
        }
    }
    #pragma unroll
    for (int mt = 0; mt < 4; mt++) {
        float r0 = __builtin_amdgcn_rcpf(e[mt][0]);
        float r1 = __builtin_amdgcn_rcpf(e[mt][1]);
        float r2 = __builtin_amdgcn_rcpf(e[mt][2]);
        float r3 = __builtin_amdgcn_rcpf(e[mt][3]);
        uint2 o;
        o.x = pack2bf(r0, r1);
        o.y = pack2bf(r2, r3);
        int mtg = (M0 >> 4) + mt;
        int ltg = (L0 >> 4) + wave;
        *(uint2*)(drpT + ((((size_t)b * 128 + mtg) * 128 + ltg) << 8) + lane * 4) = o;
    }
}

// ---------------------------------------------------------------------------
// attn_pv: block = (b, h, 128 l). m-loop in 64-steps; K double-buffered in LDS
// with register prefetch -> ONE barrier per step. Wave w owns l-rows
// [32w,32w+32) for both S and PV phases, so the P tile is wave-private (no
// S->PV barrier). V^T B-frags direct from global (L2-resident).
// ---------------------------------------------------------------------------
__global__ __launch_bounds__(256, 4) void attn_pv(
    const unsigned short* __restrict__ qb, const unsigned short* __restrict__ kb,
    const unsigned short* __restrict__ vbt, const unsigned short* __restrict__ drpT,
    unsigned short* __restrict__ cb)
{
    __shared__ __align__(16) unsigned short Ks[2][64 * 64];  // 2 x 8 KB
    __shared__ __align__(16) unsigned short Ps[128 * 64];    // 16 KB
    const int tid = threadIdx.x, wave = tid >> 6, lane = tid & 63;
    const int quad = lane >> 4, lr = lane & 15;
    const int L0 = blockIdx.x * 128, h = blockIdx.y, b = blockIdx.z;
    const size_t head = (size_t)(b * 16 + h);
    const unsigned short* qbase = qb + (head << 17);
    const unsigned short* kbase = kb + (head << 17);
    const unsigned short* vtb   = vbt + (head << 17);        // [64][2048]
    const int krow = tid >> 3, ksb = tid & 7;                // K stage: rows krow, krow+32
    const int kphys = (ksb ^ (krow & 7)) * 8;
    const int e7 = lr & 7;

    // Q B-fragments (rows L0 + wave*32 + j*16 + lr), loaded once
    short8 qf[2][2];
    #pragma unroll
    for (int j = 0; j < 2; j++) {
        const unsigned short* qr = qbase + (size_t)(L0 + wave * 32 + j * 16 + lr) * 64;
        qf[j][0] = *(const short8*)(qr + quad * 8);
        qf[j][1] = *(const short8*)(qr + 32 + quad * 8);
    }

    floatx4 oacc[2][4];
    #pragma unroll
    for (int i = 0; i < 2; i++)
        #pragma unroll
        for (int j = 0; j < 4; j++) oacc[i][j] = (floatx4)0.0f;

    // prologue: stage K(0)
    {
        short8 a = *(const short8*)(kbase + (size_t)krow * 64 + ksb * 8);
        short8 c = *(const short8*)(kbase + (size_t)(krow + 32) * 64 + ksb * 8);
        *(short8*)&Ks[0][krow * 64 + kphys] = a;
        *(short8*)&Ks[0][(krow + 32) * 64 + kphys] = c;
    }
    __syncthreads();

    for (int t = 0; t < 32; t++) {
        const int M0 = t * 64;
        const unsigned short* ksrc = &Ks[t & 1][0];
        // prefetch next K tile into registers (latency overlapped with compute)
        short8 nka, nkc;
        if (t < 31) {
            nka = *(const short8*)(kbase + (size_t)(M0 + 64 + krow) * 64 + ksb * 8);
            nkc = *(const short8*)(kbase + (size_t)(M0 + 64 + krow + 32) * 64 + ksb * 8);
        }
        // ---- S phase: S^T tiles (mt 0..3) x (lt = wave*2 + j), P -> wave-private LDS
        #pragma unroll
        for (int mt = 0; mt < 4; mt++) {
            const int rk = mt * 16 + lr;
            short8 kf0 = *(const short8*)&ksrc[rk * 64 + (quad ^ e7) * 8];
            short8 kf1 = *(const short8*)&ksrc[rk * 64 + ((4 + quad) ^ e7) * 8];
            const int mtg = (M0 >> 4) + mt;
            #pragma unroll
            for (int j = 0; j < 2; j++) {
                const int ltg = (L0 >> 4) + wave * 2 + j;
                uint2 du = *(const uint2*)(drpT + ((((size_t)b * 128 + mtg) * 128 + ltg) << 8) + lane * 4);
                floatx4 s = (floatx4)0.0f;
                s = __builtin_amdgcn_mfma_f32_16x16x32_bf16(kf0, qf[j][0], s, 0, 0, 0);
                s = __builtin_amdgcn_mfma_f32_16x16x32_bf16(kf1, qf[j][1], s, 0, 0, 0);
                float r0 = __uint_as_float(du.x << 16);
                float r1 = __uint_as_float(du.x & 0xffff0000u);
                float r2 = __uint_as_float(du.y << 16);
                float r3 = __uint_as_float(du.y & 0xffff0000u);
                float p0 = __builtin_amdgcn_exp2f(s[0]) * r0;
                float p1 = __builtin_amdgcn_exp2f(s[1]) * r1;
                float p2 = __builtin_amdgcn_exp2f(s[2]) * r2;
                float p3 = __builtin_amdgcn_exp2f(s[3]) * r3;
                uint2 o;
                o.x = pack2bf(p0, p1);
                o.y = pack2bf(p2, p3);
                const int l_loc = wave * 32 + j * 16 + lr;
                const int lb16 = mt * 2 + (quad >> 1);
                const int phys16 = lb16 ^ e7;
                *(uint2*)&Ps[l_loc * 64 + phys16 * 8 + (quad & 1) * 4] = o;
            }
        }
        // ---- PV phase: wave-private P rows -> no barrier needed
        #pragma unroll
        for (int f = 0; f < 2; f++) {
            short8 pf[2];
            #pragma unroll
            for (int i2 = 0; i2 < 2; i2++) {
                const int lrow = wave * 32 + i2 * 16 + lr;
                const int phys16 = (f * 4 + quad) ^ e7;
                pf[i2] = *(const short8*)&Ps[lrow * 64 + phys16 * 8];
            }
            #pragma unroll
            for (int j2 = 0; j2 < 4; j2++) {
                const int nrow = j2 * 16 + lr;
                short8 vf = *(const short8*)(vtb + (size_t)nrow * 2048 + M0 + f * 32 + quad * 8);
                #pragma unroll
                for (int i2 = 0; i2 < 2; i2++)
                    oacc[i2][j2] = __builtin_amdgcn_mfma_f32_16x16x32_bf16(pf[i2], vf, oacc[i2][j2], 0, 0, 0);
            }
        }
        // ---- store prefetched K into the other buffer; single barrier
        if (t < 31) {
            unsigned short* kdst = &Ks[(t + 1) & 1][0];
            *(short8*)&kdst[krow * 64 + kphys] = nka;
            *(short8*)&kdst[(krow + 32) * 64 + kphys] = nkc;
            __syncthreads();
        }
    }
    // epilogue: concat layout cb[b*2048 + l][h*64 + n]
    #pragma unroll
    for (int i2 = 0; i2 < 2; i2++)
        #pragma unroll
        for (int j2 = 0; j2 < 4; j2++)
            #pragma unroll
            for (int r = 0; r < 4; r++) {
                int row = L0 + wave * 32 + i2 * 16 + quad * 4 + r;
                int col = h * 64 + j2 * 16 + lr;
                cb[(size_t)(b * 2048 + row) * 1024 + col] = f2bf(oacc[i2][j2][r]);
            }
}

extern "C" void kernel_launch(void* const* d_in, const int* in_sizes, int n_in,
                              void* d_out, int out_size, void* d_ws, size_t ws_size,
                              hipStream_t stream) {
    const float* x    = (const float*)d_in[0];   // [4,2048,1024]
    const float* wqkv = (const float*)d_in[1];   // [1024,3072]
    const float* wo   = (const float*)d_in[2];   // [1024,1024]
    float* out = (float*)d_out;                  // [4,2048,1024] fp32

    // workspace: 100,663,296 bytes with overlays
    unsigned short* W = (unsigned short*)d_ws;
    unsigned short* qb   = W;                    // [4,16,2048,64] pre-scaled Q
    unsigned short* kb   = W + 8388608;          // [4,16,2048,64]
    unsigned short* vbt  = W + 16777216;         // [4,16,64,2048] V^T
    unsigned short* drpT = W + 25165824;         // [4][128mt][128lt][256] recip denom
    unsigned short* cb   = W + 41943040;         // [8192,1024] concat
    // overlays (lifetime-disjoint):
    unsigned short* xb    = drpT;                // bf16 x   (dead before denom)
    unsigned short* wqkvT = drpT + 8388608;      // bf16 wqkv^T [3072][1024]
    unsigned short* vb    = cb;                  // V row-major (dead before pv)
    unsigned short* woT   = drpT;                // bf16 wo^T [1024][1024] (after pv)

    cvt_bf16  <<<4096, 256, 0, stream>>>(x, xb, 1048576);
    tcvt      <<<dim3(48, 16), 256, 0, stream>>>(wqkv, wqkvT, 1024, 3072);
    qkv_gemm  <<<dim3(24, 64), 256, 0, stream>>>(xb, wqkvT, qb, kb, vb);
    vtrans    <<<dim3(32, 64), 256, 0, stream>>>(vb, vbt);
    attn_denom<<<dim3(32, 32, 4), 256, 0, stream>>>(qb, kb, drpT);
    attn_pv   <<<dim3(16, 16, 4), 256, 0, stream>>>(qb, kb, vbt, drpT, cb);
    tcvt      <<<dim3(16, 16), 256, 0, stream>>>(wo, woT, 1024, 1024);
    out_gemm  <<<dim3(8, 64), 256, 0, stream>>>(cb, woT, out);
}